// Round 1
// baseline (61.328 us; speedup 1.0000x reference)
//
#include <hip/hip_runtime.h>

#define NPTS 16384
#define BT   256      // threads per block
#define P    4        // source rows per thread
#define ROWS (BT * P) // 1024 rows per block
#define CH   1024     // target-chunk points staged in LDS (16 KB)

// Pack (x,y,z) -> (x,y,z, 0.5*(x^2+y^2+z^2)) for both clouds.
__global__ void chamfer_prep(const float* __restrict__ s,
                             const float* __restrict__ t,
                             float4* __restrict__ s4,
                             float4* __restrict__ t4) {
    int i = blockIdx.x * blockDim.x + threadIdx.x;
    if (i < NPTS) {
        float x = s[3 * i], y = s[3 * i + 1], z = s[3 * i + 2];
        s4[i] = make_float4(x, y, z, 0.5f * (x * x + y * y + z * z));
        x = t[3 * i]; y = t[3 * i + 1]; z = t[3 * i + 2];
        t4[i] = make_float4(x, y, z, 0.5f * (x * x + y * y + z * z));
    }
}

// One block: 1024 source rows x 1024-target chunk, one direction.
// grid = (row_blocks=16, chunks=16, dirs=2)
__global__ __launch_bounds__(BT, 4)
void chamfer_main(const float4* __restrict__ s4,
                  const float4* __restrict__ t4,
                  unsigned* __restrict__ out) {
    const int dir = blockIdx.z;
    const float4* __restrict__ src = dir ? t4 : s4;
    const float4* __restrict__ tgt = dir ? s4 : t4;
    unsigned* __restrict__ o = out + dir * NPTS;

    __shared__ float4 lt[CH];
    const int chunk0 = blockIdx.y * CH;
    for (int i = threadIdx.x; i < CH; i += BT)
        lt[i] = tgt[chunk0 + i];
    __syncthreads();

    const int row0 = blockIdx.x * ROWS + threadIdx.x;
    float nx[P], ny[P], nz[P], s2h[P], m[P];
#pragma unroll
    for (int p = 0; p < P; ++p) {
        float4 s = src[row0 + p * BT];
        nx[p] = -s.x; ny[p] = -s.y; nz[p] = -s.z;
        s2h[p] = s.w;
        m[p] = 1e30f;
    }

#pragma unroll 4
    for (int j = 0; j < CH; ++j) {
        float4 t = lt[j];   // uniform address -> LDS broadcast, no conflicts
#pragma unroll
        for (int p = 0; p < P; ++p) {
            float d = fmaf(nx[p], t.x, t.w);   // t2h - sx*tx
            d = fmaf(ny[p], t.y, d);
            d = fmaf(nz[p], t.z, d);
            m[p] = fminf(m[p], d);             // min of d/2 - s2h
        }
    }

#pragma unroll
    for (int p = 0; p < P; ++p) {
        float dist = fmaxf(2.0f * (m[p] + s2h[p]), 0.0f);
        atomicMin(&o[row0 + p * BT], __float_as_uint(dist));
    }
}

extern "C" void kernel_launch(void* const* d_in, const int* in_sizes, int n_in,
                              void* d_out, int out_size, void* d_ws, size_t ws_size,
                              hipStream_t stream) {
    const float* src = (const float*)d_in[0];
    const float* tgt = (const float*)d_in[1];

    float4* s4 = (float4*)d_ws;
    float4* t4 = s4 + NPTS;

    // Pack + precompute half-squared-norms.
    chamfer_prep<<<(NPTS + BT - 1) / BT, BT, 0, stream>>>(src, tgt, s4, t4);

    // Init outputs to a huge positive float: bytes 0x7F -> 0x7F7F7F7F ~ 3.39e38.
    hipMemsetAsync(d_out, 0x7F, (size_t)out_size * sizeof(float), stream);

    dim3 grid(NPTS / ROWS, NPTS / CH, 2);
    chamfer_main<<<grid, BT, 0, stream>>>(s4, t4, (unsigned*)d_out);
}